// Round 2
// baseline (206.934 us; speedup 1.0000x reference)
//
#include <hip/hip_runtime.h>

// GraphConvolution: out = relu(D^-1/2 (2I - adj) D^-1/2 (input@weight) + b)
// N=8192, F_in=512, F_out=256. All inputs f32; internal GEMMs in fp16 MFMA
// (fp16 not bf16: the N=8192 cancellation-heavy sum needs 2^-12 rounding).
//
// R1 change: k3's B operand (S'^T, 4 MB, L2-resident) is loaded global->VGPR
// directly (it has ZERO intra-CU reuse, LDS staging was pure overhead);
// only the A tile (shared by all 8 waves) goes through LDS. One barrier/step.

typedef _Float16 h4 __attribute__((ext_vector_type(4)));
typedef _Float16 h8 __attribute__((ext_vector_type(8)));
typedef float f4 __attribute__((ext_vector_type(4)));

__device__ __forceinline__ void gload_lds16(const void* g, void* l) {
    __builtin_amdgcn_global_load_lds(
        (const __attribute__((address_space(1))) void*)g,
        (__attribute__((address_space(3))) void*)l, 16, 0, 0);
}

// ---------------------------------------------------------------------------
// k0: weight [512][256] f32 -> W^T [256 j][512 k] fp16, XOR-swizzled within
// each 128B (64-elem) k-chunk: byte ^= ((j&7)<<4). Lets k2 global_load_lds it
// linearly while ds_reads apply the same XOR (bank-conflict-free b128 reads).
__global__ __launch_bounds__(256) void k0_wt(const float* __restrict__ weight,
                                             char* __restrict__ wt) {
    const int idx = blockIdx.x * 256 + threadIdx.x;   // 131072 total
    const int k = idx >> 8, j = idx & 255;
    const _Float16 h = (_Float16)weight[idx];
    const int off = j * 1024 + ((k >> 6) << 7) + (((k & 63) << 1) ^ ((j & 7) << 4));
    *(_Float16*)(wt + off) = h;
}

// ---------------------------------------------------------------------------
// k1: dinv[r] = 1/sqrt(2 + sum_k adj[r][k])
__global__ __launch_bounds__(256) void k1_deg(const float* __restrict__ adj,
                                              float* __restrict__ dinv) {
    const int r = blockIdx.x;
    const float4* rp = (const float4*)(adj + (size_t)r * 8192);
    const int t = threadIdx.x;
    float s = 0.f;
#pragma unroll
    for (int i = 0; i < 8; ++i) {
        float4 v = rp[t + i * 256];
        s += (v.x + v.y) + (v.z + v.w);
    }
#pragma unroll
    for (int off = 32; off > 0; off >>= 1) s += __shfl_down(s, off, 64);
    __shared__ float part[4];
    if ((t & 63) == 0) part[t >> 6] = s;
    __syncthreads();
    if (t == 0) {
        float deg = (part[0] + part[1]) + (part[2] + part[3]);
        dinv[r] = 1.0f / sqrtf(2.0f + deg);
    }
}

// ---------------------------------------------------------------------------
// k2: support = input @ weight; writes S'^T[j][k] = dinv[k]*support[k][j] as
// fp16, transposed, LINEAR layout (k3 consumes it straight into registers).
// Block: 64 rows x 256 cols, 8 waves, K=512 in 8 steps of BK=64.
__global__ __launch_bounds__(512) void k2_support(const float* __restrict__ input,
                                                  const char* __restrict__ wt,
                                                  const float* __restrict__ dinv,
                                                  char* __restrict__ sT) {
    __shared__ char smem[8192 + 32768];   // A [64][128B] + B [256][128B]
    const int t = threadIdx.x, w = t >> 6, l = t & 63;
    const int r0 = (int)blockIdx.x * 64;
    const int ar = t >> 4, ac4 = t & 15;
    const int bj = l >> 3, bb = (l & 7) * 16;

    f4 acc[4][2] = {};

    for (int kt = 0; kt < 8; ++kt) {
        const int k0 = kt * 64;
        __syncthreads();
        // stage A: input rows -> fp16, swizzled
#pragma unroll
        for (int hh = 0; hh < 2; ++hh) {
            const int row = ar + hh * 32;
            float4 v = *(const float4*)(input + (size_t)(r0 + row) * 512 + k0 + ac4 * 4);
            h4 h;
            h[0] = (_Float16)v.x; h[1] = (_Float16)v.y;
            h[2] = (_Float16)v.z; h[3] = (_Float16)v.w;
            *(h4*)(smem + row * 128 + ((ac4 * 8) ^ ((row & 7) << 4))) = h;
        }
        // stage B: W^T tile [256][64] fp16 via global_load_lds (pre-swizzled src)
#pragma unroll
        for (int q = 0; q < 4; ++q) {
            const int c = w * 4 + q;
            gload_lds16(wt + (size_t)(c * 8 + bj) * 1024 + kt * 128 + bb,
                        smem + 8192 + c * 1024);
        }
        __syncthreads();
#pragma unroll
        for (int kk = 0; kk < 2; ++kk) {
            const int kb = (kk * 32 + ((l >> 4) << 3)) << 1;
            h8 b[2];
#pragma unroll
            for (int n = 0; n < 2; ++n) {
                const int j = w * 32 + n * 16 + (l & 15);
                b[n] = *(const h8*)(smem + 8192 + j * 128 + (kb ^ ((j & 7) << 4)));
            }
#pragma unroll
            for (int m = 0; m < 4; ++m) {
                const int r = m * 16 + (l & 15);
                h8 a = *(const h8*)(smem + r * 128 + (kb ^ ((r & 7) << 4)));
                acc[m][0] = __builtin_amdgcn_mfma_f32_16x16x32_f16(a, b[0], acc[m][0], 0, 0, 0);
                acc[m][1] = __builtin_amdgcn_mfma_f32_16x16x32_f16(a, b[1], acc[m][1], 0, 0, 0);
            }
        }
    }
    // epilogue: S'^T[j][k] fp16, linear. C/D: col=l&15, row=(l>>4)*4+reg.
#pragma unroll
    for (int m = 0; m < 4; ++m)
#pragma unroll
        for (int n = 0; n < 2; ++n) {
            const int j = w * 32 + n * 16 + (l & 15);
            const int k0r = r0 + m * 16 + ((l >> 4) << 2);
            h4 h;
#pragma unroll
            for (int r = 0; r < 4; ++r)
                h[r] = (_Float16)(dinv[k0r + r] * acc[m][n][r]);
            *(h4*)(sT + (size_t)j * 16384 + (size_t)k0r * 2) = h;
        }
}

// ---------------------------------------------------------------------------
// k3: out[i][j] = relu(dinv[i] * sum_k (2*I - adj)[i][k] * S'T[j][k] + b[j])
// BM=32, BN=256, BK=64, 8 waves, 256 blocks (1/CU).
// A: global f32 -> reg (depth-1 prefetch) -> fp16 diag-transform -> LDS
//    (XOR-swizzled, double-buffered, 2x4KB). One barrier per K-step.
// B: global fp16 -> VGPR fragments directly (ping-pong regs, no LDS).
__global__ __launch_bounds__(512, 2) void k3_spmm(const float* __restrict__ adj,
                                                  const char* __restrict__ sT,
                                                  const float* __restrict__ dinv,
                                                  const float* __restrict__ bias,
                                                  float* __restrict__ out) {
    __shared__ __align__(16) char smem[2][4096];   // A tiles [32 rows][128 B]
    const int t = threadIdx.x;
    const int w = t >> 6, l = t & 63;
    const int i0 = (int)blockIdx.x * 32;

    const int arow = t >> 4;            // 0..31 (16 threads per row)
    const int ac4 = t & 15;             // float4 index along k
    const int arow_g = i0 + arow;
    const float* aptr = adj + (size_t)arow_g * 8192 + ac4 * 4;
    const int a_off = arow * 128 + ((ac4 * 8) ^ ((arow & 7) << 4));

    f4 acc[2][2] = {};

    auto loadB = [&](int kt, h8 (&b)[2][2]) {
#pragma unroll
        for (int kk = 0; kk < 2; ++kk)
#pragma unroll
            for (int n = 0; n < 2; ++n) {
                const int j = w * 32 + n * 16 + (l & 15);
                const int kg = kt * 64 + kk * 32 + ((l >> 4) << 3);
                b[kk][n] = *(const h8*)(sT + ((size_t)j * 8192 + kg) * 2);
            }
    };
    auto writeA = [&](int kt, const float4 v, char* buf) {
        const int kg = kt * 64 + ac4 * 4;
        h4 h;  // A~ = 2I - adj folded here
        h[0] = (_Float16)((arow_g == kg    ) ? 2.0f - v.x : -v.x);
        h[1] = (_Float16)((arow_g == kg + 1) ? 2.0f - v.y : -v.y);
        h[2] = (_Float16)((arow_g == kg + 2) ? 2.0f - v.z : -v.z);
        h[3] = (_Float16)((arow_g == kg + 3) ? 2.0f - v.w : -v.w);
        *(h4*)(buf + a_off) = h;
    };
    auto compute = [&](const char* A, const h8 (&b)[2][2]) {
#pragma unroll
        for (int kk = 0; kk < 2; ++kk) {
            const int kb = (kk * 32 + ((l >> 4) << 3)) << 1;
            h8 a[2];
#pragma unroll
            for (int m = 0; m < 2; ++m) {
                const int r = m * 16 + (l & 15);
                a[m] = *(const h8*)(A + r * 128 + (kb ^ ((r & 7) << 4)));
            }
#pragma unroll
            for (int m = 0; m < 2; ++m)
#pragma unroll
                for (int n = 0; n < 2; ++n)
                    acc[m][n] = __builtin_amdgcn_mfma_f32_16x16x32_f16(a[m], b[kk][n], acc[m][n], 0, 0, 0);
        }
    };

    h8 b0[2][2], b1[2][2];
    float4 aN;

    // prologue: tile 0 staged, tile 1's adj row in regs
    {
        float4 a0 = *(const float4*)aptr;
        loadB(0, b0);
        writeA(0, a0, smem[0]);
        aN = *(const float4*)(aptr + 64);
        __syncthreads();
    }

    auto step = [&](int kt, h8 (&bc)[2][2], h8 (&bn)[2][2], char* curb, char* nxtb) {
        if (kt + 1 < 128) {
            loadB(kt + 1, bn);          // next B into ping-pong regs
            writeA(kt + 1, aN, nxtb);   // consume prefetched adj row
        }
        if (kt + 2 < 128)
            aN = *(const float4*)(aptr + (size_t)(kt + 2) * 64);
        compute(curb, bc);
        __syncthreads();
    };

    for (int kt2 = 0; kt2 < 128; kt2 += 2) {
        step(kt2,     b0, b1, smem[0], smem[1]);
        step(kt2 + 1, b1, b0, smem[1], smem[0]);
    }

    // epilogue: out = relu(dinv[i]*acc + b[j]) straight to d_out
#pragma unroll
    for (int m = 0; m < 2; ++m)
#pragma unroll
        for (int n = 0; n < 2; ++n) {
            const int j = w * 32 + n * 16 + (l & 15);
            const float bjv = bias[j];
            const int ib = i0 + m * 16 + ((l >> 4) << 2);
            float* op = out + (size_t)ib * 256 + j;
#pragma unroll
            for (int r = 0; r < 4; ++r) {
                float v = dinv[ib + r] * acc[m][n][r] + bjv;
                op[(size_t)r * 256] = v > 0.f ? v : 0.f;
            }
        }
}

// ---------------------------------------------------------------------------
extern "C" void kernel_launch(void* const* d_in, const int* in_sizes, int n_in,
                              void* d_out, int out_size, void* d_ws, size_t ws_size,
                              hipStream_t stream) {
    const float* input  = (const float*)d_in[0];   // [8192][512]
    const float* adj    = (const float*)d_in[1];   // [8192][8192]
    const float* weight = (const float*)d_in[2];   // [512][256]
    const float* bias   = (const float*)d_in[3];   // [256]
    float* out = (float*)d_out;                    // [8192][256]

    char* ws = (char*)d_ws;
    float* dinv = (float*)ws;                 // 32 KB
    char*  wt   = ws + 32768;                 // 256 KB  (W^T fp16, swizzled)
    char*  sT   = ws + 294912;                // 4 MB    (S'^T fp16, linear)

    k0_wt<<<512, 256, 0, stream>>>(weight, wt);
    k1_deg<<<8192, 256, 0, stream>>>(adj, dinv);
    k2_support<<<128, 512, 0, stream>>>(input, wt, dinv, sT);
    k3_spmm<<<256, 512, 0, stream>>>(adj, sT, dinv, bias, out);
}

// Round 3
// 143.204 us; speedup vs baseline: 1.4450x; 1.4450x over previous
//
#include <hip/hip_runtime.h>

// GraphConvolution: out = relu(D^-1/2 (2I - adj) D^-1/2 (input@weight) + b)
// N=8192, F_in=512, F_out=256. fp16 MFMA internally (needs 2^-12 rounding).
//
// R3: k3 restructured: BM=64 x BN=256, K split 4-ways -> 512 blocks (2/CU).
// A (adj tile): reg-stage f32 -> diag-transform -> fp16 -> swizzled LDS.
// B (sT): global_load_lds from pre-swizzled sT (both-sides swizzle rule).
// Partial f32 sums -> ws/d_out; k4 fuses dinv/bias/relu + reduction.

typedef _Float16 h4 __attribute__((ext_vector_type(4)));
typedef _Float16 h8 __attribute__((ext_vector_type(8)));
typedef float f4 __attribute__((ext_vector_type(4)));

__device__ __forceinline__ void gload_lds16(const void* g, void* l) {
    __builtin_amdgcn_global_load_lds(
        (const __attribute__((address_space(1))) void*)g,
        (__attribute__((address_space(3))) void*)l, 16, 0, 0);
}

// ---------------------------------------------------------------------------
// k0: weight [512][256] f32 -> W^T [256 j][512 k] fp16, XOR-swizzled within
// each 128B k-chunk: byte ^= ((j&7)<<4).
__global__ __launch_bounds__(256) void k0_wt(const float* __restrict__ weight,
                                             char* __restrict__ wt) {
    const int idx = blockIdx.x * 256 + threadIdx.x;   // 131072 total
    const int k = idx >> 8, j = idx & 255;
    const _Float16 h = (_Float16)weight[idx];
    const int off = j * 1024 + ((k >> 6) << 7) + (((k & 63) << 1) ^ ((j & 7) << 4));
    *(_Float16*)(wt + off) = h;
}

// ---------------------------------------------------------------------------
// k1: dinv[r] = 1/sqrt(2 + sum_k adj[r][k])
__global__ __launch_bounds__(256) void k1_deg(const float* __restrict__ adj,
                                              float* __restrict__ dinv) {
    const int r = blockIdx.x;
    const float4* rp = (const float4*)(adj + (size_t)r * 8192);
    const int t = threadIdx.x;
    float s = 0.f;
#pragma unroll
    for (int i = 0; i < 8; ++i) {
        float4 v = rp[t + i * 256];
        s += (v.x + v.y) + (v.z + v.w);
    }
#pragma unroll
    for (int off = 32; off > 0; off >>= 1) s += __shfl_down(s, off, 64);
    __shared__ float part[4];
    if ((t & 63) == 0) part[t >> 6] = s;
    __syncthreads();
    if (t == 0) {
        float deg = (part[0] + part[1]) + (part[2] + part[3]);
        dinv[r] = 1.0f / sqrtf(2.0f + deg);
    }
}

// ---------------------------------------------------------------------------
// k2: support = input @ weight; writes S'^T[j][k] = dinv[k]*support[k][j] as
// fp16, transposed + pre-swizzled (128B-chunk XOR, matches k3's ds_read XOR).
__global__ __launch_bounds__(512) void k2_support(const float* __restrict__ input,
                                                  const char* __restrict__ wt,
                                                  const float* __restrict__ dinv,
                                                  char* __restrict__ sT) {
    __shared__ char smem[8192 + 32768];   // A [64][128B] + B [256][128B]
    const int t = threadIdx.x, w = t >> 6, l = t & 63;
    const int r0 = (int)blockIdx.x * 64;
    const int ar = t >> 4, ac4 = t & 15;
    const int bj = l >> 3, bb = (l & 7) * 16;

    f4 acc[4][2] = {};

    for (int kt = 0; kt < 8; ++kt) {
        const int k0 = kt * 64;
        __syncthreads();
#pragma unroll
        for (int hh = 0; hh < 2; ++hh) {
            const int row = ar + hh * 32;
            float4 v = *(const float4*)(input + (size_t)(r0 + row) * 512 + k0 + ac4 * 4);
            h4 h;
            h[0] = (_Float16)v.x; h[1] = (_Float16)v.y;
            h[2] = (_Float16)v.z; h[3] = (_Float16)v.w;
            *(h4*)(smem + row * 128 + ((ac4 * 8) ^ ((row & 7) << 4))) = h;
        }
#pragma unroll
        for (int q = 0; q < 4; ++q) {
            const int c = w * 4 + q;
            gload_lds16(wt + (size_t)(c * 8 + bj) * 1024 + kt * 128 + bb,
                        smem + 8192 + c * 1024);
        }
        __syncthreads();
#pragma unroll
        for (int kk = 0; kk < 2; ++kk) {
            const int kb = (kk * 32 + ((l >> 4) << 3)) << 1;
            h8 b[2];
#pragma unroll
            for (int n = 0; n < 2; ++n) {
                const int j = w * 32 + n * 16 + (l & 15);
                b[n] = *(const h8*)(smem + 8192 + j * 128 + (kb ^ ((j & 7) << 4)));
            }
#pragma unroll
            for (int m = 0; m < 4; ++m) {
                const int r = m * 16 + (l & 15);
                h8 a = *(const h8*)(smem + r * 128 + (kb ^ ((r & 7) << 4)));
                acc[m][0] = __builtin_amdgcn_mfma_f32_16x16x32_f16(a, b[0], acc[m][0], 0, 0, 0);
                acc[m][1] = __builtin_amdgcn_mfma_f32_16x16x32_f16(a, b[1], acc[m][1], 0, 0, 0);
            }
        }
    }
    // S'^T[j][k] fp16, swizzled: off = j*16384 + (k>>6)*128 + ((2*(k&63)) ^ ((j&7)<<4))
#pragma unroll
    for (int m = 0; m < 4; ++m)
#pragma unroll
        for (int n = 0; n < 2; ++n) {
            const int j = w * 32 + n * 16 + (l & 15);
            const int k0r = r0 + m * 16 + ((l >> 4) << 2);
            h4 h;
#pragma unroll
            for (int r = 0; r < 4; ++r)
                h[r] = (_Float16)(dinv[k0r + r] * acc[m][n][r]);
            const int off = j * 16384 + ((k0r >> 6) << 7) +
                            (((k0r & 63) << 1) ^ ((j & 7) << 4));
            *(h4*)(sT + off) = h;
        }
}

// ---------------------------------------------------------------------------
// k3: partial[i][j] = sum_{k in split} (2I - adj)[i][k] * S'T[j][k]
// BM=64, BN=256, BK=64, 8 waves (2M x 4N, wave tile 32x64), double-buffered.
// blockIdx.x = m-tile (128), blockIdx.y = K-split. LDS 80KB -> 2 blocks/CU.
__global__ __launch_bounds__(512, 4) void k3_spmm(const float* __restrict__ adj,
                                                  const char* __restrict__ sT,
                                                  float* __restrict__ part,
                                                  float* __restrict__ out,
                                                  int steps) {
    __shared__ __align__(16) char smem[2][40960];  // per buf: A 8KB + B 32KB
    const int t = threadIdx.x;
    const int w = t >> 6, l = t & 63;
    const int wm = w >> 2, wn = w & 3;
    const int i0 = (int)blockIdx.x * 64;
    const int ks0 = (int)blockIdx.y * steps * 64;

    // A staging map: row = t>>3 (0..63), 8 consecutive k per thread
    const int arow = t >> 3;
    const int ak8 = (t & 7) * 8;
    const int arow_g = i0 + arow;
    const float4* aptr = (const float4*)(adj + (size_t)arow_g * 8192 + ks0 + ak8);
    const int a_off = arow * 128 + (((t & 7) << 4) ^ ((arow & 7) << 4));

    // B staging map
    const int bj = l >> 3, bb = (l & 7) * 16;
    const int chunk0 = ks0 >> 6;

    f4 acc[2][4] = {};

    auto stageB = [&](int kt, int buf) {
        char* bl = smem[buf] + 8192;
#pragma unroll
        for (int q = 0; q < 4; ++q) {
            const int c = w * 4 + q;
            gload_lds16(sT + (size_t)(c * 8 + bj) * 16384 + (chunk0 + kt) * 128 + bb,
                        bl + c * 1024);
        }
    };
    auto loadA = [&](int kt, float4& v0, float4& v1) {
        v0 = aptr[kt * 16];
        v1 = aptr[kt * 16 + 1];
    };
    auto writeA = [&](int kt, const float4 v0, const float4 v1, int buf) {
        const int kg = ks0 + kt * 64 + ak8;
        h8 h;
        const float* vv = (const float*)&v0;
#pragma unroll
        for (int e = 0; e < 4; ++e)
            h[e] = (_Float16)((arow_g == kg + e) ? 2.0f - vv[e] : -vv[e]);
        const float* vw = (const float*)&v1;
#pragma unroll
        for (int e = 0; e < 4; ++e)
            h[4 + e] = (_Float16)((arow_g == kg + 4 + e) ? 2.0f - vw[e] : -vw[e]);
        *(h8*)(smem[buf] + a_off) = h;
    };
    auto compute = [&](int buf) {
        const char* A = smem[buf];
        const char* B = smem[buf] + 8192;
#pragma unroll
        for (int kk = 0; kk < 2; ++kk) {
            const int ko = kk * 64 + ((l >> 4) << 4);   // byte offset of 2k
            h8 a[2], b[4];
#pragma unroll
            for (int m = 0; m < 2; ++m) {
                const int r = wm * 32 + m * 16 + (l & 15);
                a[m] = *(const h8*)(A + r * 128 + (ko ^ ((r & 7) << 4)));
            }
#pragma unroll
            for (int n = 0; n < 4; ++n) {
                const int j = wn * 64 + n * 16 + (l & 15);
                b[n] = *(const h8*)(B + j * 128 + (ko ^ ((j & 7) << 4)));
            }
#pragma unroll
            for (int m = 0; m < 2; ++m)
#pragma unroll
                for (int n = 0; n < 4; ++n)
                    acc[m][n] = __builtin_amdgcn_mfma_f32_16x16x32_f16(a[m], b[n], acc[m][n], 0, 0, 0);
        }
    };

    // prologue
    {
        float4 v0, v1;
        loadA(0, v0, v1);
        stageB(0, 0);
        writeA(0, v0, v1, 0);
        __syncthreads();
    }

    int cur = 0;
    for (int kt = 0; kt < steps; ++kt) {
        const bool pf = (kt + 1) < steps;
        float4 v0, v1;
        if (pf) {
            stageB(kt + 1, cur ^ 1);
            loadA(kt + 1, v0, v1);
        }
        compute(cur);
        if (pf) writeA(kt + 1, v0, v1, cur ^ 1);
        __syncthreads();
        cur ^= 1;
    }

    // write f32 partial (last split writes into d_out)
    float* dst = (blockIdx.y == gridDim.y - 1) ? out
               : part + (size_t)blockIdx.y * (8192 * 256);
#pragma unroll
    for (int m = 0; m < 2; ++m)
#pragma unroll
        for (int n = 0; n < 4; ++n) {
            const int j = wn * 64 + n * 16 + (l & 15);
            const int ib = i0 + wm * 32 + m * 16 + ((l >> 4) << 2);
#pragma unroll
            for (int r = 0; r < 4; ++r)
                dst[(size_t)(ib + r) * 256 + j] = acc[m][n][r];
        }
}

// ---------------------------------------------------------------------------
// k4: out = relu(dinv[i] * (sum of partials) + b[j]); last partial is in out.
__global__ __launch_bounds__(256) void k4_fin(const float* __restrict__ part,
                                              float* __restrict__ out,
                                              const float* __restrict__ dinv,
                                              const float* __restrict__ bias,
                                              int nsplit) {
    const int idx = blockIdx.x * 256 + threadIdx.x;   // 524288 float4 groups
    float4 s = ((const float4*)out)[idx];
    for (int sp = 0; sp < nsplit - 1; ++sp)
        s += ((const float4*)(part + (size_t)sp * (8192 * 256)))[idx];
    const float dv = dinv[idx >> 6];
    const float4 b = ((const float4*)bias)[idx & 63];
    float4 r;
    r.x = fmaxf(dv * s.x + b.x, 0.f);
    r.y = fmaxf(dv * s.y + b.y, 0.f);
    r.z = fmaxf(dv * s.z + b.z, 0.f);
    r.w = fmaxf(dv * s.w + b.w, 0.f);
    ((float4*)out)[idx] = r;
}

// ---------------------------------------------------------------------------
extern "C" void kernel_launch(void* const* d_in, const int* in_sizes, int n_in,
                              void* d_out, int out_size, void* d_ws, size_t ws_size,
                              hipStream_t stream) {
    const float* input  = (const float*)d_in[0];   // [8192][512]
    const float* adj    = (const float*)d_in[1];   // [8192][8192]
    const float* weight = (const float*)d_in[2];   // [512][256]
    const float* bias   = (const float*)d_in[3];   // [256]
    float* out = (float*)d_out;                    // [8192][256]

    char* ws = (char*)d_ws;
    float* dinv = (float*)ws;                         // 32 KB
    char*  wt   = ws + 32768;                         // 256 KB
    char*  sT   = ws + 294912;                        // 4 MB (fp16, swizzled)
    float* part = (float*)(ws + 294912 + 4194304);    // (nsplit-1) * 8 MB

    const size_t base = 294912 + 4194304;
    int nsplit = 1;
    if (ws_size >= base + 3 * 8388608) nsplit = 4;        // ~28.3 MB
    else if (ws_size >= base + 1 * 8388608) nsplit = 2;   // ~12.7 MB
    const int steps = 128 / nsplit;

    k0_wt<<<512, 256, 0, stream>>>(weight, wt);
    k1_deg<<<8192, 256, 0, stream>>>(adj, dinv);
    k2_support<<<128, 512, 0, stream>>>(input, wt, dinv, sT);
    k3_spmm<<<dim3(128, nsplit), 512, 0, stream>>>(adj, sT, part, out, steps);
    k4_fin<<<2048, 256, 0, stream>>>(part, out, dinv, bias, nsplit);
}

// Round 4
// 137.717 us; speedup vs baseline: 1.5026x; 1.0398x over previous
//
#include <hip/hip_runtime.h>

// GraphConvolution: out = relu(D^-1/2 (2I - adj) D^-1/2 (input@weight) + b)
// N=8192, F_in=512, F_out=256. fp16 MFMA internally (needs 2^-12 rounding).
//
// R4: k3 gets a counted-vmcnt pipeline (T4): adj loads via inline-asm
// global_load_dwordx4 into ping-pong regs, raw s_barrier with
// "s_waitcnt vmcnt(2) lgkmcnt(0)" so the next adj loads stay in flight
// across the barrier (never drain to 0 in the main loop). k2: 256 blocks.

typedef _Float16 h4 __attribute__((ext_vector_type(4)));
typedef _Float16 h8 __attribute__((ext_vector_type(8)));
typedef float f4 __attribute__((ext_vector_type(4)));

__device__ __forceinline__ void gload_lds16(const void* g, void* l) {
    __builtin_amdgcn_global_load_lds(
        (const __attribute__((address_space(1))) void*)g,
        (__attribute__((address_space(3))) void*)l, 16, 0, 0);
}

// two 16B adj loads via inline asm: compiler cannot attach its own vmcnt(0)
__device__ __forceinline__ void gload2(const float* p, f4& x, f4& y) {
    asm volatile("global_load_dwordx4 %0, %2, off\n\t"
                 "global_load_dwordx4 %1, %2, off offset:16"
                 : "=&v"(x), "=&v"(y)
                 : "v"(p)
                 : "memory");
}

// ---------------------------------------------------------------------------
// k0: weight [512][256] f32 -> W^T [256 j][512 k] fp16, XOR-swizzled within
// each 128B k-chunk: byte ^= ((j&7)<<4).
__global__ __launch_bounds__(256) void k0_wt(const float* __restrict__ weight,
                                             char* __restrict__ wt) {
    const int idx = blockIdx.x * 256 + threadIdx.x;   // 131072 total
    const int k = idx >> 8, j = idx & 255;
    const _Float16 h = (_Float16)weight[idx];
    const int off = j * 1024 + ((k >> 6) << 7) + (((k & 63) << 1) ^ ((j & 7) << 4));
    *(_Float16*)(wt + off) = h;
}

// ---------------------------------------------------------------------------
// k1: dinv[r] = 1/sqrt(2 + sum_k adj[r][k])
__global__ __launch_bounds__(256) void k1_deg(const float* __restrict__ adj,
                                              float* __restrict__ dinv) {
    const int r = blockIdx.x;
    const float4* rp = (const float4*)(adj + (size_t)r * 8192);
    const int t = threadIdx.x;
    float s = 0.f;
#pragma unroll
    for (int i = 0; i < 8; ++i) {
        float4 v = rp[t + i * 256];
        s += (v.x + v.y) + (v.z + v.w);
    }
#pragma unroll
    for (int off = 32; off > 0; off >>= 1) s += __shfl_down(s, off, 64);
    __shared__ float part[4];
    if ((t & 63) == 0) part[t >> 6] = s;
    __syncthreads();
    if (t == 0) {
        float deg = (part[0] + part[1]) + (part[2] + part[3]);
        dinv[r] = 1.0f / sqrtf(2.0f + deg);
    }
}

// ---------------------------------------------------------------------------
// k2: support = input @ weight; writes S'^T[j][k] = dinv[k]*support[k][j] as
// fp16, transposed + pre-swizzled. BM=32, 256 blocks, 8 waves (j-slice 32).
__global__ __launch_bounds__(512) void k2_support(const float* __restrict__ input,
                                                  const char* __restrict__ wt,
                                                  const float* __restrict__ dinv,
                                                  char* __restrict__ sT) {
    __shared__ char smem[4096 + 32768];   // A [32][128B] + B [256][128B]
    const int t = threadIdx.x, w = t >> 6, l = t & 63;
    const int r0 = (int)blockIdx.x * 32;
    const int arow = t >> 4, ak4 = t & 15;
    const int bj = l >> 3, bb = (l & 7) * 16;

    f4 acc[2][2] = {};

    for (int kt = 0; kt < 8; ++kt) {
        const int k0 = kt * 64;
        __syncthreads();
        // stage A: 32 rows x 64 k fp16, swizzled
        {
            float4 v = *(const float4*)(input + (size_t)(r0 + arow) * 512 + k0 + ak4 * 4);
            h4 h;
            h[0] = (_Float16)v.x; h[1] = (_Float16)v.y;
            h[2] = (_Float16)v.z; h[3] = (_Float16)v.w;
            *(h4*)(smem + arow * 128 + ((ak4 * 8) ^ ((arow & 7) << 4)));
            *(h4*)(smem + arow * 128 + ((ak4 * 8) ^ ((arow & 7) << 4))) = h;
        }
        // stage B: W^T tile [256][64] fp16 via global_load_lds (pre-swizzled)
#pragma unroll
        for (int q = 0; q < 4; ++q) {
            const int c = q * 8 + w;
            gload_lds16(wt + (size_t)(c * 8 + bj) * 1024 + kt * 128 + bb,
                        smem + 4096 + c * 1024);
        }
        __syncthreads();
#pragma unroll
        for (int kk = 0; kk < 2; ++kk) {
            const int ko = kk * 64 + ((l >> 4) << 4);
            h8 a[2], b[2];
#pragma unroll
            for (int m = 0; m < 2; ++m) {
                const int r = m * 16 + (l & 15);
                a[m] = *(const h8*)(smem + r * 128 + (ko ^ ((r & 7) << 4)));
            }
#pragma unroll
            for (int n = 0; n < 2; ++n) {
                const int j = w * 32 + n * 16 + (l & 15);
                b[n] = *(const h8*)(smem + 4096 + j * 128 + (ko ^ ((j & 7) << 4)));
            }
#pragma unroll
            for (int m = 0; m < 2; ++m)
#pragma unroll
                for (int n = 0; n < 2; ++n)
                    acc[m][n] = __builtin_amdgcn_mfma_f32_16x16x32_f16(a[m], b[n], acc[m][n], 0, 0, 0);
        }
    }
    // S'^T[j][k] fp16, swizzled
#pragma unroll
    for (int m = 0; m < 2; ++m)
#pragma unroll
        for (int n = 0; n < 2; ++n) {
            const int j = w * 32 + n * 16 + (l & 15);
            const int k0r = r0 + m * 16 + ((l >> 4) << 2);
            h4 h;
#pragma unroll
            for (int r = 0; r < 2; ++r) h[r] = (_Float16)(dinv[k0r + r] * acc[m][n][r]);
#pragma unroll
            for (int r = 2; r < 4; ++r) h[r] = (_Float16)(dinv[k0r + r] * acc[m][n][r]);
            const int off = j * 16384 + ((k0r >> 6) << 7) +
                            (((k0r & 63) << 1) ^ ((j & 7) << 4));
            *(h4*)(sT + off) = h;
        }
}

// ---------------------------------------------------------------------------
// k3: partial[i][j] = sum_{k in split} (2I - adj)[i][k] * S'T[j][k]
// BM=64, BN=256, BK=64, 8 waves (2M x 4N), 512 blocks (2/CU), counted-vmcnt
// pipeline: adj in asm-loaded ping-pong regs, B via gload_lds, raw barriers.
__global__ __launch_bounds__(512, 4) void k3_spmm(const float* __restrict__ adj,
                                                  const char* __restrict__ sT,
                                                  float* __restrict__ part,
                                                  float* __restrict__ out,
                                                  int steps) {
    __shared__ __align__(16) char smem[2][40960];  // per buf: A 8KB + B 32KB
    const int t = threadIdx.x;
    const int w = t >> 6, l = t & 63;
    const int wm = w >> 2, wn = w & 3;
    const int i0 = (int)blockIdx.x * 64;
    const int ks0 = (int)blockIdx.y * steps * 64;
    const int dkt = (i0 - ks0) >> 6;   // uniform: K-step holding the diagonal

    const int arow = t >> 3;            // 0..63
    const int ak8 = (t & 7) * 8;        // 8 consecutive k per thread
    const int arow_g = i0 + arow;
    const float* aptr = adj + (size_t)arow_g * 8192 + ks0 + ak8;
    const int a_off = arow * 128 + (((t & 7) << 4) ^ ((arow & 7) << 4));

    const int bj = l >> 3, bb = (l & 7) * 16;
    const int chunk0 = ks0 >> 6;

    f4 acc[2][4] = {};

    auto stageB = [&](int kt, char* buf) {
        char* bl = buf + 8192;
#pragma unroll
        for (int q = 0; q < 4; ++q) {
            const int c = w * 4 + q;
            gload_lds16(sT + (size_t)(c * 8 + bj) * 16384 + (chunk0 + kt) * 128 + bb,
                        bl + c * 1024);
        }
    };
    auto writeA = [&](char* buf, int kt, const f4 x, const f4 y) {
        const int kg = ks0 + kt * 64 + ak8;
        h8 h;
        if (kt == dkt) {
#pragma unroll
            for (int e = 0; e < 4; ++e)
                h[e] = (_Float16)((arow_g == kg + e) ? 2.0f - x[e] : -x[e]);
#pragma unroll
            for (int e = 0; e < 4; ++e)
                h[4 + e] = (_Float16)((arow_g == kg + 4 + e) ? 2.0f - y[e] : -y[e]);
        } else {
#pragma unroll
            for (int e = 0; e < 4; ++e) h[e] = (_Float16)(-x[e]);
#pragma unroll
            for (int e = 0; e < 4; ++e) h[4 + e] = (_Float16)(-y[e]);
        }
        *(h8*)(buf + a_off) = h;
    };
    auto compute = [&](const char* buf) {
        const char* A = buf;
        const char* B = buf + 8192;
#pragma unroll
        for (int kk = 0; kk < 2; ++kk) {
            const int ko = kk * 64 + ((l >> 4) << 4);
            h8 a[2], b[4];
#pragma unroll
            for (int m = 0; m < 2; ++m) {
                const int r = wm * 32 + m * 16 + (l & 15);
                a[m] = *(const h8*)(A + r * 128 + (ko ^ ((r & 7) << 4)));
            }
#pragma unroll
            for (int n = 0; n < 4; ++n) {
                const int j = wn * 64 + n * 16 + (l & 15);
                b[n] = *(const h8*)(B + j * 128 + (ko ^ ((j & 7) << 4)));
            }
#pragma unroll
            for (int m = 0; m < 2; ++m)
#pragma unroll
                for (int n = 0; n < 4; ++n)
                    acc[m][n] = __builtin_amdgcn_mfma_f32_16x16x32_f16(a[m], b[n], acc[m][n], 0, 0, 0);
        }
    };

    f4 fx0, fy0, fx1, fy1;   // ping-pong adj reg buffers (static names, no dyn idx)

    // prologue: A(0),A(1) in flight; B(0) staged; A(0)->LDS; barrier (A(1) flows)
    gload2(aptr, fx0, fy0);
    gload2(aptr + 64, fx1, fy1);
    stageB(0, smem[0]);
    asm volatile("s_waitcnt vmcnt(6)" : "+v"(fx0), "+v"(fy0) :: "memory");
    __builtin_amdgcn_sched_barrier(0);
    writeA(smem[0], 0, fx0, fy0);
    asm volatile("s_waitcnt vmcnt(2) lgkmcnt(0)\n\ts_barrier" ::: "memory");
    __builtin_amdgcn_sched_barrier(0);

    // body(kt): stage B(kt+1); load A(kt+2) into freed regs; write A(kt+1);
    // compute(kt); barrier with vmcnt(2) (A(kt+2) stays in flight).
    auto body = [&](int kt, f4& xc, f4& yc, f4& xn, f4& yn, char* bufC, char* bufN) {
        stageB(kt + 1, bufN);                                   // 4 vm ops
        gload2(aptr + (size_t)(kt + 2) * 64, xc, yc);           // 2 vm ops
        asm volatile("s_waitcnt vmcnt(6)" : "+v"(xn), "+v"(yn) :: "memory");
        __builtin_amdgcn_sched_barrier(0);
        writeA(bufN, kt + 1, xn, yn);
        compute(bufC);
        asm volatile("s_waitcnt vmcnt(2) lgkmcnt(0)\n\ts_barrier" ::: "memory");
        __builtin_amdgcn_sched_barrier(0);
    };

    for (int kt2 = 0; kt2 + 2 < steps; kt2 += 2) {
        body(kt2,     fx0, fy0, fx1, fy1, smem[0], smem[1]);
        body(kt2 + 1, fx1, fy1, fx0, fy0, smem[1], smem[0]);
    }
    // peeled kt = steps-2 (cur=0): no new A load
    {
        stageB(steps - 1, smem[1]);                             // 4 vm ops
        asm volatile("s_waitcnt vmcnt(4)" : "+v"(fx1), "+v"(fy1) :: "memory");
        __builtin_amdgcn_sched_barrier(0);
        writeA(smem[1], steps - 1, fx1, fy1);
        compute(smem[0]);
        asm volatile("s_waitcnt vmcnt(0) lgkmcnt(0)\n\ts_barrier" ::: "memory");
        __builtin_amdgcn_sched_barrier(0);
        compute(smem[1]);                                       // kt = steps-1
    }

    // write f32 partial (last split writes into d_out)
    float* dst = (blockIdx.y == gridDim.y - 1) ? out
               : part + (size_t)blockIdx.y * (8192 * 256);
#pragma unroll
    for (int m = 0; m < 2; ++m)
#pragma unroll
        for (int n = 0; n < 4; ++n) {
            const int j = wn * 64 + n * 16 + (l & 15);
            const int ib = i0 + wm * 32 + m * 16 + ((l >> 4) << 2);
#pragma unroll
            for (int r = 0; r < 4; ++r)
                dst[(size_t)(ib + r) * 256 + j] = acc[m][n][r];
        }
}

// ---------------------------------------------------------------------------
// k4: out = relu(dinv[i] * (sum of partials) + b[j]); last partial is in out.
__global__ __launch_bounds__(256) void k4_fin(const float* __restrict__ part,
                                              float* __restrict__ out,
                                              const float* __restrict__ dinv,
                                              const float* __restrict__ bias,
                                              int nsplit) {
    const int idx = blockIdx.x * 256 + threadIdx.x;   // 524288 float4 groups
    float4 s = ((const float4*)out)[idx];
    for (int sp = 0; sp < nsplit - 1; ++sp)
        s += ((const float4*)(part + (size_t)sp * (8192 * 256)))[idx];
    const float dv = dinv[idx >> 6];
    const float4 b = ((const float4*)bias)[idx & 63];
    float4 r;
    r.x = fmaxf(dv * s.x + b.x, 0.f);
    r.y = fmaxf(dv * s.y + b.y, 0.f);
    r.z = fmaxf(dv * s.z + b.z, 0.f);
    r.w = fmaxf(dv * s.w + b.w, 0.f);
    ((float4*)out)[idx] = r;
}

// ---------------------------------------------------------------------------
extern "C" void kernel_launch(void* const* d_in, const int* in_sizes, int n_in,
                              void* d_out, int out_size, void* d_ws, size_t ws_size,
                              hipStream_t stream) {
    const float* input  = (const float*)d_in[0];   // [8192][512]
    const float* adj    = (const float*)d_in[1];   // [8192][8192]
    const float* weight = (const float*)d_in[2];   // [512][256]
    const float* bias   = (const float*)d_in[3];   // [256]
    float* out = (float*)d_out;                    // [8192][256]

    char* ws = (char*)d_ws;
    float* dinv = (float*)ws;                         // 32 KB
    char*  wt   = ws + 32768;                         // 256 KB
    char*  sT   = ws + 294912;                        // 4 MB (fp16, swizzled)
    float* part = (float*)(ws + 294912 + 4194304);    // (nsplit-1) * 8 MB

    const size_t base = 294912 + 4194304;
    int nsplit = 1;
    if (ws_size >= base + 3 * 8388608) nsplit = 4;        // ~28.3 MB
    else if (ws_size >= base + 1 * 8388608) nsplit = 2;   // ~12.7 MB
    const int steps = 128 / nsplit;

    k0_wt<<<512, 256, 0, stream>>>(weight, wt);
    k1_deg<<<8192, 256, 0, stream>>>(adj, dinv);
    k2_support<<<256, 512, 0, stream>>>(input, wt, dinv, sT);
    k3_spmm<<<dim3(128, nsplit), 512, 0, stream>>>(adj, sT, part, out, steps);
    k4_fin<<<2048, 256, 0, stream>>>(part, out, dinv, bias, nsplit);
}